// Round 10
// baseline (53.431 us; speedup 1.0000x reference)
//
#include <hip/hip_runtime.h>
#include <math.h>
#include <stdint.h>

#define NHEAD 4
#define DD 100
#define NW 39            // word rows
#define BLOCK 256
#define NS 3             // sites per block; grid = 4800/NS = 1600 (all resident)

__global__ __launch_bounds__(BLOCK, 6) void ts_enc(
    const float* __restrict__ x,       // [4800][40][100]
    const float* __restrict__ w_att,   // [4][100]
    const float* __restrict__ b_att,   // [4][100]
    float* __restrict__ out)           // [4800][400]
{
    __shared__ float tile[40 * DD];      // 16 KB: row0 = type_emb, rows 1..39 = words
    __shared__ float scp[4][NHEAD][40];  // [wave-partial][head][n]  (2.56 KB)

    const int tid  = threadIdx.x;
    const int wv   = __builtin_amdgcn_readfirstlane(tid >> 6);
    const int lane = tid & 63;
    const int site0 = blockIdx.x * NS;

    // ---- prologue: site0 tile -> regs -> LDS ----
    float4 pf[4];
    {
        const float* xs = x + (size_t)site0 * (40 * DD);
        #pragma unroll
        for (int i = 0; i < 4; ++i) {
            const int cf = i * BLOCK + tid;
            if (cf < 1000) pf[i] = *(const float4*)(xs + cf * 4);
        }
    }
    #pragma unroll
    for (int i = 0; i < 4; ++i) {
        const int cf = i * BLOCK + tid;
        if (cf < 1000) *(float4*)(tile + cf * 4) = pf[i];
    }
    __syncthreads();                                    // B1: tile ready

    for (int s = 0; s < NS; ++s) {
        const int site = site0 + s;

        // ---- T14: issue NEXT site's global loads now; consumed after Phase C ----
        if (s + 1 < NS) {
            const float* xn = x + (size_t)(site + 1) * (40 * DD);
            #pragma unroll
            for (int i = 0; i < 4; ++i) {
                const int cf = i * BLOCK + tid;
                if (cf < 1000) pf[i] = *(const float4*)(xn + cf * 4);
            }
        }

        // ---- Phase A: d-chunks split across waves, lane = n, all 4 heads ----
        // te*leaky(p) == (0.65*te)*p + (0.35*te)*|p|  (|p| = free modifier)
        const bool act  = lane < NW;
        const int  nrow = act ? lane : NW - 1;          // clamp idle lanes
        const float* wrow = tile + (1 + nrow) * DD;
        float acc[NHEAD] = {0.f, 0.f, 0.f, 0.f};

        for (int c = wv; c < 25; c += 4) {
            const float4 te4 = *(const float4*)(tile + c * 4);   // LDS broadcast
            const float4 v4  = *(const float4*)(wrow + c * 4);   // per-lane row
            const float a65x = 0.65f * te4.x, a35x = 0.35f * te4.x;
            const float a65y = 0.65f * te4.y, a35y = 0.35f * te4.y;
            const float a65z = 0.65f * te4.z, a35z = 0.35f * te4.z;
            const float a65w = 0.65f * te4.w, a35w = 0.35f * te4.w;
            #pragma unroll
            for (int h = 0; h < NHEAD; ++h) {
                const float4 w4 = *(const float4*)(w_att + h * DD + c * 4); // s_load
                const float4 b4 = *(const float4*)(b_att + h * DD + c * 4);
                float p0 = fmaf(v4.x, w4.x, b4.x);
                float p1 = fmaf(v4.y, w4.y, b4.y);
                float p2 = fmaf(v4.z, w4.z, b4.z);
                float p3 = fmaf(v4.w, w4.w, b4.w);
                float t  = fmaf(a65x, p0, fmaf(a35x, fabsf(p0), acc[h]));
                t        = fmaf(a65y, p1, fmaf(a35y, fabsf(p1), t));
                t        = fmaf(a65z, p2, fmaf(a35z, fabsf(p2), t));
                acc[h]   = fmaf(a65w, p3, fmaf(a35w, fabsf(p3), t));
            }
        }
        if (act) {
            scp[wv][0][lane] = acc[0];
            scp[wv][1][lane] = acc[1];
            scp[wv][2][lane] = acc[2];
            scp[wv][3][lane] = acc[3];
        }
        __syncthreads();                                // B2: scp ready

        // ---- Phase B: softmax in-wave (wave wv = head wv, lane = n) ----
        float sc = -INFINITY;
        if (act) sc = (scp[0][wv][lane] + scp[1][wv][lane])
                    + (scp[2][wv][lane] + scp[3][wv][lane]);
        float mx = sc;
        #pragma unroll
        for (int off = 32; off; off >>= 1) mx = fmaxf(mx, __shfl_xor(mx, off));
        float p = act ? __expf(sc - mx) : 0.f;
        float sm = p;
        #pragma unroll
        for (int off = 32; off; off >>= 1) sm += __shfl_xor(sm, off);
        const float a = p / sm;       // lane n holds att[head=wv][n]

        // ---- Phase C: wave = head, lane = d-pair (50 active); att via readlane
        //      (SGPR operand feeds v_fma directly); tile rows still valid ----
        const int l2 = lane < 50 ? lane : 49;
        const float* wb = tile + DD + l2 * 2;
        float ox = 0.f, oy = 0.f;
        #pragma unroll
        for (int n = 0; n < NW; ++n) {
            const float attn = __builtin_bit_cast(float,
                __builtin_amdgcn_readlane(__builtin_bit_cast(int, a), n));
            const float2 wd = *(const float2*)(wb + n * DD);
            ox = fmaf(attn, wd.x, ox);
            oy = fmaf(attn, wd.y, oy);
        }
        if (lane < 50) {
            float2 o2 = make_float2(ox, oy);
            *(float2*)(out + (size_t)site * (NHEAD * DD) + wv * DD + lane * 2) = o2;
        }
        __syncthreads();                                // B3: all tile/scp reads done

        // ---- write prefetched tile for next site (vmcnt wait folded here) ----
        if (s + 1 < NS) {
            #pragma unroll
            for (int i = 0; i < 4; ++i) {
                const int cf = i * BLOCK + tid;
                if (cf < 1000) *(float4*)(tile + cf * 4) = pf[i];
            }
            __syncthreads();                            // B1': tile ready
        }
    }
}

extern "C" void kernel_launch(void* const* d_in, const int* in_sizes, int n_in,
                              void* d_out, int out_size, void* d_ws, size_t ws_size,
                              hipStream_t stream) {
    const float* x     = (const float*)d_in[0];
    const float* w_att = (const float*)d_in[1];
    const float* b_att = (const float*)d_in[2];
    float* out = (float*)d_out;

    const int sites = 8 * 30 * 20;           // 4800
    ts_enc<<<sites / NS, BLOCK, 0, stream>>>(x, w_att, b_att, out);
}

// Round 11
// 32.521 us; speedup vs baseline: 1.6429x; 1.6429x over previous
//
#include <hip/hip_runtime.h>
#include <math.h>
#include <stdint.h>

#define NHEAD 4
#define DD 100
#define NW 39            // word rows
#define BLOCK 128        // 2 waves; wave w owns heads 2w, 2w+1

typedef float v2f __attribute__((ext_vector_type(2)));
typedef __attribute__((address_space(3))) uint32_t lds_t;
typedef const __attribute__((address_space(1))) uint32_t glb_t;

__global__ __launch_bounds__(BLOCK) void ts_enc(
    const float* __restrict__ x,       // [4800][40][100]
    const float* __restrict__ w_att,   // [4][100]
    const float* __restrict__ b_att,   // [4][100]
    float* __restrict__ out)           // [4800][400]
{
    __shared__ float tile[40 * DD];    // 16000 B exactly — keeps 9 blocks/CU

    const int tid  = threadIdx.x;
    const int wv   = __builtin_amdgcn_readfirstlane(tid >> 6);   // 0,1
    const int lane = tid & 63;
    const float* xsite = x + (size_t)blockIdx.x * (40 * DD);

    // ---- stage tile: async global->LDS, 16 B/lane, 1000 float4 chunks ----
    #pragma unroll
    for (int i = 0; i < 8; ++i) {
        const int cf = i * BLOCK + tid;
        if (cf < 1000) {
            glb_t* g = (glb_t*)(xsite + cf * 4);
            lds_t* l = (lds_t*)(tile + (i * BLOCK + wv * 64) * 4);
            __builtin_amdgcn_global_load_lds(g, l, 16, 0, 0);
        }
    }
    __syncthreads();   // the ONLY barrier: both waves' DMA done, tile stable

    // ---- Phase A: lane = n; this wave's 2 heads; packed (v_pk_fma) over d ----
    // leaky(p) = max(p, 0.3p) exactly; te from global (uniform -> s_load/K$)
    const bool act  = lane < NW;
    const int  nrow = act ? lane : NW - 1;            // clamp idle lanes
    const float* wrow = tile + (1 + nrow) * DD;
    const int h0 = wv * 2;

    v2f acA0 = {0,0}, acB0 = {0,0};   // head h0
    v2f acA1 = {0,0}, acB1 = {0,0};   // head h0+1

    #pragma unroll
    for (int c = 0; c < 25; ++c) {
        const v2f x01 = *(const v2f*)(wrow + c * 4);          // ds_read
        const v2f x23 = *(const v2f*)(wrow + c * 4 + 2);
        const v2f t01 = *(const v2f*)(xsite + c * 4);         // uniform global
        const v2f t23 = *(const v2f*)(xsite + c * 4 + 2);
        #pragma unroll
        for (int hh = 0; hh < 2; ++hh) {
            const int h = h0 + hh;
            const v2f w01 = *(const v2f*)(w_att + h * DD + c * 4);
            const v2f w23 = *(const v2f*)(w_att + h * DD + c * 4 + 2);
            const v2f b01 = *(const v2f*)(b_att + h * DD + c * 4);
            const v2f b23 = *(const v2f*)(b_att + h * DD + c * 4 + 2);
            const v2f p01 = x01 * w01 + b01;
            const v2f p23 = x23 * w23 + b23;
            const v2f l01 = __builtin_elementwise_max(p01, 0.3f * p01);
            const v2f l23 = __builtin_elementwise_max(p23, 0.3f * p23);
            if (hh == 0) { acA0 = t01 * l01 + acA0; acB0 = t23 * l23 + acB0; }
            else         { acA1 = t01 * l01 + acA1; acB1 = t23 * l23 + acB1; }
        }
    }
    const float sc0 = (acA0.x + acA0.y) + (acB0.x + acB0.y);
    const float sc1 = (acA1.x + acA1.y) + (acB1.x + acB1.y);

    // ---- Phase B: raw exp, exactly like the reference (no max-subtract,
    //      scores are O(1) by construction); no cross-lane ops at all ----
    const float e0 = act ? __expf(sc0) : 0.f;   // lane n holds e[h0][n]
    const float e1 = act ? __expf(sc1) : 0.f;   // lane n holds e[h0+1][n]

    // ---- Phase C: lane = d-pair (50 active); e via readlane (SGPR operand);
    //      unnormalized accumulate + denominator sum in the same loop ----
    const int l2 = lane < 50 ? lane : 49;
    const float* wb = tile + DD + l2 * 2;
    v2f o0 = {0,0}, o1 = {0,0};
    float s0 = 0.f, s1 = 0.f;
    #pragma unroll
    for (int n = 0; n < NW; ++n) {
        const float a0 = __builtin_bit_cast(float,
            __builtin_amdgcn_readlane(__builtin_bit_cast(int, e0), n));
        const float a1 = __builtin_bit_cast(float,
            __builtin_amdgcn_readlane(__builtin_bit_cast(int, e1), n));
        const v2f wd = *(const v2f*)(wb + n * DD);   // 50-lane b64, 2-way banks
        o0 = a0 * wd + o0;
        o1 = a1 * wd + o1;
        s0 += a0;
        s1 += a1;
    }
    const float r0 = 1.f / s0;    // uniform; all-zero site -> s=39, out=0 exact
    const float r1 = 1.f / s1;
    if (lane < 50) {
        float* ob = out + (size_t)blockIdx.x * (NHEAD * DD) + h0 * DD + lane * 2;
        const v2f q0 = o0 * r0;
        const v2f q1 = o1 * r1;
        *(v2f*)(ob)      = q0;
        *(v2f*)(ob + DD) = q1;
    }
}

extern "C" void kernel_launch(void* const* d_in, const int* in_sizes, int n_in,
                              void* d_out, int out_size, void* d_ws, size_t ws_size,
                              hipStream_t stream) {
    const float* x     = (const float*)d_in[0];
    const float* w_att = (const float*)d_in[1];
    const float* b_att = (const float*)d_in[2];
    float* out = (float*)d_out;

    const int sites = 8 * 30 * 20;   // 4800
    ts_enc<<<sites, BLOCK, 0, stream>>>(x, w_att, b_att, out);
}

// Round 12
// 27.501 us; speedup vs baseline: 1.9429x; 1.1826x over previous
//
#include <hip/hip_runtime.h>
#include <math.h>
#include <stdint.h>

#define NHEAD 4
#define DD 100
#define NW 39            // word rows
#define BLOCK 256

typedef float v2f __attribute__((ext_vector_type(2)));
typedef __attribute__((address_space(3))) uint32_t lds_t;
typedef const __attribute__((address_space(1))) uint32_t glb_t;

__global__ __launch_bounds__(BLOCK, 6) void ts_enc(
    const float* __restrict__ x,       // [4800][40][100]
    const float* __restrict__ w_att,   // [4][100]
    const float* __restrict__ b_att,   // [4][100]
    float* __restrict__ out)           // [4800][400]
{
    __shared__ float tile[40 * DD];      // 16000 B: row0 = type_emb, rows 1..39 = words
    __shared__ float scp[NHEAD][4][40];  // [head][wave-partial][n] — conflict-free b32

    const int tid  = threadIdx.x;
    const int wv   = __builtin_amdgcn_readfirstlane(tid >> 6);
    const int lane = tid & 63;
    const float* xsite = x + (size_t)blockIdx.x * (40 * DD);

    // ---- stage site tile: async global->LDS, 16 B/lane, 1000 float4 chunks ----
    #pragma unroll
    for (int i = 0; i < 4; ++i) {
        const int cf = i * BLOCK + tid;
        if (cf < 1000) {
            glb_t* g = (glb_t*)(xsite + cf * 4);
            lds_t* l = (lds_t*)(tile + (i * BLOCK + wv * 64) * 4);
            __builtin_amdgcn_global_load_lds(g, l, 16, 0, 0);
        }
    }
    __syncthreads();                                   // barrier 1: tile ready

    // ---- Phase A: d-split, COMPILE-TIME chunks; lane = n; packed math ----
    // leaky(p) = max(p, 0.3p): bit-identical to where(p>=0, p, 0.3*p)
    const bool act  = lane < NW;
    const int  nrow = act ? lane : NW - 1;             // clamp idle lanes
    const float* wrow = tile + (1 + nrow) * DD;

    v2f accA[NHEAD] = {{0,0},{0,0},{0,0},{0,0}};
    v2f accB[NHEAD] = {{0,0},{0,0},{0,0},{0,0}};

#define ABODY(cc) { \
        const int c_ = (cc); \
        const v2f x01 = *(const v2f*)(wrow + c_ * 4); \
        const v2f x23 = *(const v2f*)(wrow + c_ * 4 + 2); \
        const v2f t01 = *(const v2f*)(tile + c_ * 4); \
        const v2f t23 = *(const v2f*)(tile + c_ * 4 + 2); \
        _Pragma("unroll") \
        for (int h = 0; h < NHEAD; ++h) { \
            const v2f w01 = *(const v2f*)(w_att + h * DD + c_ * 4); \
            const v2f w23 = *(const v2f*)(w_att + h * DD + c_ * 4 + 2); \
            const v2f b01 = *(const v2f*)(b_att + h * DD + c_ * 4); \
            const v2f b23 = *(const v2f*)(b_att + h * DD + c_ * 4 + 2); \
            const v2f p01 = x01 * w01 + b01; \
            const v2f p23 = x23 * w23 + b23; \
            const v2f l01 = __builtin_elementwise_max(p01, 0.3f * p01); \
            const v2f l23 = __builtin_elementwise_max(p23, 0.3f * p23); \
            accA[h] = t01 * l01 + accA[h]; \
            accB[h] = t23 * l23 + accB[h]; \
        } }

    #pragma unroll
    for (int j = 0; j < 6; ++j) ABODY(wv * 6 + j)      // compile-time trip, pipelined
    if (wv == 0) ABODY(24)                             // uniform branch, chunk 25
#undef ABODY

    if (act) {
        #pragma unroll
        for (int h = 0; h < NHEAD; ++h)
            scp[h][wv][lane] = (accA[h].x + accA[h].y) + (accB[h].x + accB[h].y);
    }
    __syncthreads();                                   // barrier 2: scp ready

    // ---- Phase B: wave wv = head wv; raw exp (as reference), sum tree only ----
    float sc = 0.f;
    if (act) sc = (scp[wv][0][lane] + scp[wv][1][lane])
                + (scp[wv][2][lane] + scp[wv][3][lane]);
    const float e = act ? __expf(sc) : 0.f;            // lane n holds e[head=wv][n]
    float sm = e;
    #pragma unroll
    for (int off = 32; off; off >>= 1) sm += __shfl_xor(sm, off);
    const float att = e / sm;                          // att[head=wv][n] in lane n

    // ---- Phase C: wave = head, lane = d-pair (50 active); att via v_readlane
    //      (SGPR operand feeds v_fma directly); tile stable, NO barrier ----
    const int l2 = lane < 50 ? lane : 49;
    const float* wb = tile + DD + l2 * 2;
    float ox = 0.f, oy = 0.f;
    #pragma unroll
    for (int n = 0; n < NW; ++n) {
        const float attn = __builtin_bit_cast(float,
            __builtin_amdgcn_readlane(__builtin_bit_cast(int, att), n));
        const v2f wd = *(const v2f*)(wb + n * DD);     // 50-lane b64, ~2-way banks
        ox = fmaf(attn, wd.x, ox);
        oy = fmaf(attn, wd.y, oy);
    }
    if (lane < 50) {
        const v2f o = {ox, oy};
        *(v2f*)(out + (size_t)blockIdx.x * (NHEAD * DD) + wv * DD + lane * 2) = o;
    }
}

extern "C" void kernel_launch(void* const* d_in, const int* in_sizes, int n_in,
                              void* d_out, int out_size, void* d_ws, size_t ws_size,
                              hipStream_t stream) {
    const float* x     = (const float*)d_in[0];
    const float* w_att = (const float*)d_in[1];
    const float* b_att = (const float*)d_in[2];
    float* out = (float*)d_out;

    const int sites = 8 * 30 * 20;   // 4800
    ts_enc<<<sites, BLOCK, 0, stream>>>(x, w_att, b_att, out);
}